// Round 5
// baseline (508.852 us; speedup 1.0000x reference)
//
#include <hip/hip_runtime.h>

// GCN: 2x GCNConv(sym-norm, self-loops) + mean-pool + linear head.
// Round 5: fp8(e4m3, x16-scaled) gather arrays, 8-lane-subgroup gather
// (16 edges in flight/wave), fused GEMM1+GEMM2 via LDS h1 tile,
// layer-2 agg fused with pooling. Weights stay bf16 (systematic error).

#define FEAT 128
#define TILE 16384   // edges per bucketing workgroup

typedef __attribute__((ext_vector_type(8))) short short8;    // 8 bf16
typedef __attribute__((ext_vector_type(4))) float float4v;   // 4 fp32 acc
typedef __attribute__((ext_vector_type(2))) float floatx2;

__device__ __forceinline__ unsigned int f2b(float f) {       // rne bf16 (as uint)
    unsigned int u = __float_as_uint(f);
    return (u + 0x7fffu + ((u >> 16) & 1u)) >> 16;
}

// decode 4 fp8 (one uint) -> acc[0..3] +=
__device__ __forceinline__ void dec4(unsigned int q, float* acc) {
    floatx2 lo = __builtin_amdgcn_cvt_pk_f32_fp8(q, false);
    floatx2 hi = __builtin_amdgcn_cvt_pk_f32_fp8(q, true);
    acc[0] += lo[0]; acc[1] += lo[1]; acc[2] += hi[0]; acc[3] += hi[1];
}
__device__ __forceinline__ void dec16(uint4 q, float* acc) {
    dec4(q.x, acc); dec4(q.y, acc + 4); dec4(q.z, acc + 8); dec4(q.w, acc + 12);
}

// ---------------- bucketed CSR build (bucket = dst>>10) ----------------

__global__ __launch_bounds__(1024) void k_p1(const int* __restrict__ dst,
                                             int* __restrict__ cnt, int E, int B, int NW) {
    __shared__ int h[64];
    int t = threadIdx.x, w = blockIdx.x;
    if (t < B) h[t] = 0;
    __syncthreads();
    int e0 = w * TILE, e1 = min(e0 + TILE, E);
    for (int e = e0 + t; e < e1; e += 1024) atomicAdd(&h[dst[e] >> 10], 1);
    __syncthreads();
    if (t < B) cnt[t * NW + w] = h[t];      // bucket-major
}

__global__ __launch_bounds__(1024) void k_bscan(int* __restrict__ cnt, int L) {
    __shared__ int s[1024];
    int t = threadIdx.x;
    int v[3]; int sum = 0;
#pragma unroll
    for (int j = 0; j < 3; ++j) {
        int idx = t * 3 + j;
        int x = (idx < L) ? cnt[idx] : 0;
        v[j] = sum; sum += x;
    }
    s[t] = sum;
    __syncthreads();
    for (int d = 1; d < 1024; d <<= 1) {
        int x = (t >= d) ? s[t - d] : 0;
        __syncthreads();
        s[t] += x;
        __syncthreads();
    }
    int pre = (t > 0) ? s[t - 1] : 0;
#pragma unroll
    for (int j = 0; j < 3; ++j) {
        int idx = t * 3 + j;
        if (idx < L) cnt[idx] = pre + v[j];
    }
}

__global__ __launch_bounds__(1024) void k_p3(const int* __restrict__ src,
                                             const int* __restrict__ dst,
                                             const int* __restrict__ cnt,
                                             unsigned int* __restrict__ ebuf,
                                             int E, int B, int NW) {
    __shared__ int cur[64];
    int t = threadIdx.x, w = blockIdx.x;
    if (t < B) cur[t] = cnt[t * NW + w];
    __syncthreads();
    int e0 = w * TILE, e1 = min(e0 + TILE, E);
    for (int e = e0 + t; e < e1; e += 1024) {
        int d = dst[e], s = src[e];
        int p = atomicAdd(&cur[d >> 10], 1);
        ebuf[p] = ((unsigned int)d << 16) | (unsigned int)s;
    }
}

__global__ __launch_bounds__(1024) void k_p4a(const unsigned int* __restrict__ ebuf,
                                              const int* __restrict__ cnt,
                                              int* __restrict__ degi, float* __restrict__ isd,
                                              int E, int B, int NW, int N) {
    __shared__ int h[1024];
    int t = threadIdx.x, b = blockIdx.x;
    h[t] = 0;
    __syncthreads();
    int s0 = cnt[b * NW];
    int s1 = (b + 1 < B) ? cnt[(b + 1) * NW] : E;
    for (int e = s0 + t; e < s1; e += 1024)
        atomicAdd(&h[(ebuf[e] >> 16) & 1023], 1);
    __syncthreads();
    int node = (b << 10) + t;
    if (node < N) {
        int d = h[t] + 1;                    // +1 self-loop
        degi[node] = d;
        isd[node] = rsqrtf((float)d);
    }
}

__global__ __launch_bounds__(1024) void k_p4b(const unsigned int* __restrict__ ebuf,
                                              const int* __restrict__ cnt,
                                              const int* __restrict__ off,
                                              unsigned short* __restrict__ csr,
                                              int E, int B, int NW, int N) {
    __shared__ int cur[1024];
    int t = threadIdx.x, b = blockIdx.x;
    int node = (b << 10) + t;
    cur[t] = (node < N) ? off[node] : 0;
    __syncthreads();
    int s0 = cnt[b * NW];
    int s1 = (b + 1 < B) ? cnt[(b + 1) * NW] : E;
    for (int e = s0 + t; e < s1; e += 1024) {
        unsigned int v = ebuf[e];
        int p = atomicAdd(&cur[(v >> 16) & 1023], 1);
        csr[p] = (unsigned short)(v & 0xffffu);
    }
}

// ---------------- node scans ----------------

__global__ void k_scan1(const int* __restrict__ degi, int* __restrict__ off,
                        int* __restrict__ bsum, int n) {
    __shared__ int s[1024];
    int t = threadIdx.x;
    int i = blockIdx.x * 1024 + t;
    int c = (i < n) ? (degi[i] - 1) : 0;
    s[t] = c;
    __syncthreads();
    for (int d = 1; d < 1024; d <<= 1) {
        int v = (t >= d) ? s[t - d] : 0;
        __syncthreads();
        s[t] += v;
        __syncthreads();
    }
    if (i < n) off[i] = s[t] - c;
    if (t == 1023) bsum[blockIdx.x] = s[t];
}

__global__ void k_scan2(int* __restrict__ bsum, int nb) {
    if (threadIdx.x == 0 && blockIdx.x == 0) {
        int run = 0;
        for (int b = 0; b < nb; ++b) { int v = bsum[b]; bsum[b] = run; run += v; }
    }
}

__global__ void k_scan3(int* __restrict__ off, const int* __restrict__ bsum,
                        int n, int total) {
    int i = blockIdx.x * blockDim.x + threadIdx.x;
    if (i < n) off[i] += bsum[i >> 10];
    if (i == n) off[n] = total;
}

// ---------------- casts ----------------

// xq[4i..4i+3] = fp8(16 * isd[row] * x[4i..4i+3]); also zero pooled slots
__global__ void k_scalecast(const float* __restrict__ x, const float* __restrict__ isd,
                            unsigned int* __restrict__ xq, float* __restrict__ pooled,
                            int total4) {
    int i = blockIdx.x * blockDim.x + threadIdx.x;
    if (i < 128) pooled[i * 16] = 0.f;
    if (i >= total4) return;
    float w = isd[i >> 5] * 16.f;
    float4 v = ((const float4*)x)[i];
    unsigned int u = __builtin_amdgcn_cvt_pk_fp8_f32(v.x * w, v.y * w, 0u, false);
    u = __builtin_amdgcn_cvt_pk_fp8_f32(v.z * w, v.w * w, u, true);
    xq[i] = u;
}

// both weights -> bf16 MFMA B-fragment order, one launch
// out[((kt*NT+nt)*64+lane)*8+j] = W[kt*32+(lane>>4)*8+j][nt*16+(lane&15)]
__device__ __forceinline__ void wswz_one(const float* W, unsigned short* out,
                                         int N, int tid) {
    int lane = tid & 63, f = tid >> 6;
    int NT = N >> 4;
    int nt = f % NT, kt = f / NT;
    int m = lane & 15, quad = lane >> 4;
    short8 pk;
#pragma unroll
    for (int j = 0; j < 8; ++j)
        pk[j] = (short)f2b(W[(size_t)(kt * 32 + quad * 8 + j) * N + nt * 16 + m]);
    *(short8*)(out + (size_t)tid * 8) = pk;
}

__global__ void k_wswz(const float* __restrict__ W1, unsigned short* __restrict__ w1z,
                       const float* __restrict__ W2, unsigned short* __restrict__ w2z) {
    int tid = blockIdx.x * blockDim.x + threadIdx.x;
    if (tid < 4096) wswz_one(W1, w1z, 256, tid);          // 128x256
    else if (tid < 8192) wswz_one(W2, w2z, 128, tid - 4096); // 256x128
}

// ---------------- aggregation ----------------
// acc[n] = sum_{s in N(n)} Xq[s] + Xq[n]   (Xq pre-scaled by 16*isd[src])
// EPI 0: out bf16 rows of isd[n]/16 * acc   (layer 1)
// EPI 1: pooled[f*16] += relu(isd[n]/16 * acc + b2[f])  (layer 2 + pool)
// 8 subgroups of 8 lanes; each subgroup owns one edge (uint4 = 16 feats/lane).

template <int EPI>
__global__ __launch_bounds__(256) void k_agg8(const uint4* __restrict__ Xq,
                                              const int* __restrict__ off,
                                              const unsigned short* __restrict__ csr,
                                              const float* __restrict__ isd,
                                              const float* __restrict__ b2,
                                              uint4* __restrict__ outb,
                                              float* __restrict__ pooled, int n) {
    __shared__ float sblk[128];
    int tid = threadIdx.x;
    if (EPI == 1) {
        if (tid < 128) sblk[tid] = 0.f;
        __syncthreads();
    }
    int wid  = (blockIdx.x * 256 + tid) >> 6;    // one wave per node
    int lane = tid & 63;
    int g = lane >> 3, sub = lane & 7;           // subgroup, lane-in-subgroup
    bool act = wid < n;
    int beg = 0, end = 0;
    if (act) { beg = off[wid]; end = off[wid + 1]; }
    float acc[16];
#pragma unroll
    for (int j = 0; j < 16; ++j) acc[j] = 0.f;
    if (act && g == 0) dec16(Xq[(size_t)wid * 8 + sub], acc);   // self term
    int e = beg + g;
    for (; e + 8 < end; e += 16) {               // 2 edges per subgroup in flight
        int s0 = csr[e], s1 = csr[e + 8];
        uint4 q0 = Xq[(size_t)s0 * 8 + sub];
        uint4 q1 = Xq[(size_t)s1 * 8 + sub];
        dec16(q0, acc);
        dec16(q1, acc);
    }
    if (e < end) dec16(Xq[(size_t)csr[e] * 8 + sub], acc);
    // reduce across 8 subgroups
#pragma unroll
    for (int j = 0; j < 16; ++j) acc[j] += __shfl_xor(acc[j], 8);
#pragma unroll
    for (int j = 0; j < 16; ++j) acc[j] += __shfl_xor(acc[j], 16);
#pragma unroll
    for (int j = 0; j < 16; ++j) acc[j] += __shfl_xor(acc[j], 32);

    if (EPI == 0) {
        if (act && g == 0) {
            float s = isd[wid] * 0.0625f;
            uint4 o0, o1;
            o0.x = f2b(acc[0] * s)  | (f2b(acc[1] * s)  << 16);
            o0.y = f2b(acc[2] * s)  | (f2b(acc[3] * s)  << 16);
            o0.z = f2b(acc[4] * s)  | (f2b(acc[5] * s)  << 16);
            o0.w = f2b(acc[6] * s)  | (f2b(acc[7] * s)  << 16);
            o1.x = f2b(acc[8] * s)  | (f2b(acc[9] * s)  << 16);
            o1.y = f2b(acc[10] * s) | (f2b(acc[11] * s) << 16);
            o1.z = f2b(acc[12] * s) | (f2b(acc[13] * s) << 16);
            o1.w = f2b(acc[14] * s) | (f2b(acc[15] * s) << 16);
            outb[(size_t)wid * 16 + sub * 2]     = o0;
            outb[(size_t)wid * 16 + sub * 2 + 1] = o1;
        }
    } else {
        if (act && g == 0) {
            float s = isd[wid] * 0.0625f;
#pragma unroll
            for (int j = 0; j < 16; ++j) {
                int f = sub * 16 + j;
                atomicAdd(&sblk[f], fmaxf(acc[j] * s + b2[f], 0.f));
            }
        }
        __syncthreads();
        if (tid < 128) atomicAdd(&pooled[tid * 16], sblk[tid]);
    }
}

// ---------------- fused GEMM1+GEMM2 ----------------
// stage1: h1 = relu(A@W1 + b1)   (A bf16 [M,128], W1 128x256) -> LDS tile
// stage2: t2q = fp8(16*isd[row] * (h1@W2))   (W2 256x128)

__global__ __launch_bounds__(256) void k_gemm12(const unsigned short* __restrict__ A,
                                                const unsigned short* __restrict__ W1z,
                                                const float* __restrict__ b1,
                                                const unsigned short* __restrict__ W2z,
                                                const float* __restrict__ isd,
                                                unsigned char* __restrict__ t2q, int M) {
    __shared__ unsigned short h1s[64 * 272];     // 64 rows x 256 cols, stride 272
    int tid = threadIdx.x;
    int lane = tid & 63, wm = tid >> 6;
    int m = lane & 15, quad = lane >> 4;

    long arow = (long)blockIdx.x * 64 + wm * 16 + m;
    if (arow >= M) arow = M - 1;
    const short8* Ap  = (const short8*)(A + (size_t)arow * 128);
    const short8* W1p = (const short8*)W1z + lane;

    float4v acc1[16];
    float4v zero = {0.f, 0.f, 0.f, 0.f};
#pragma unroll
    for (int nt = 0; nt < 16; ++nt) acc1[nt] = zero;
#pragma unroll
    for (int kt = 0; kt < 4; ++kt) {
        short8 a = Ap[kt * 4 + quad];
#pragma unroll
        for (int nt = 0; nt < 16; ++nt)
            acc1[nt] = __builtin_amdgcn_mfma_f32_16x16x32_bf16(a, W1p[(kt * 16 + nt) * 64],
                                                               acc1[nt], 0, 0, 0);
    }
    int r0 = wm * 16 + quad * 4;                 // block-local rows
#pragma unroll
    for (int nt = 0; nt < 16; ++nt) {
        int col = nt * 16 + m;
        float bz = b1[col];
#pragma unroll
        for (int reg = 0; reg < 4; ++reg) {
            float v = fmaxf(acc1[nt][reg] + bz, 0.f);
            h1s[(r0 + reg) * 272 + col] = (unsigned short)f2b(v);
        }
    }
    __syncthreads();

    float4v acc2[8];
#pragma unroll
    for (int nt = 0; nt < 8; ++nt) acc2[nt] = zero;
    const short8* W2p = (const short8*)W2z + lane;
    int rloc = wm * 16 + m;
#pragma unroll
    for (int kt = 0; kt < 8; ++kt) {
        short8 a2 = *(const short8*)(h1s + rloc * 272 + kt * 32 + quad * 8);
#pragma unroll
        for (int nt = 0; nt < 8; ++nt)
            acc2[nt] = __builtin_amdgcn_mfma_f32_16x16x32_bf16(a2, W2p[(kt * 8 + nt) * 64],
                                                               acc2[nt], 0, 0, 0);
    }
    int gr0 = blockIdx.x * 64 + wm * 16 + quad * 4;
    float sc[4];
#pragma unroll
    for (int reg = 0; reg < 4; ++reg) {
        int r = gr0 + reg;
        sc[reg] = (r < M ? isd[r] : 0.f) * 16.f;
    }
#pragma unroll
    for (int nt = 0; nt < 8; ++nt) {
        int col = nt * 16 + m;
#pragma unroll
        for (int reg = 0; reg < 4; ++reg) {
            int gr = gr0 + reg;
            if (gr < M) {
                float v = acc2[nt][reg] * sc[reg];
                unsigned int b = __builtin_amdgcn_cvt_pk_fp8_f32(v, v, 0u, false) & 0xffu;
                t2q[(size_t)gr * 128 + col] = (unsigned char)b;
            }
        }
    }
}

// ---------------- head ----------------

__global__ void k_final(const float* __restrict__ pooled,
                        const float* __restrict__ Wfc,
                        const float* __restrict__ bfc,
                        float* __restrict__ out, float invN) {
    __shared__ float s[128];
    int t = threadIdx.x;
    s[t] = pooled[t * 16] * invN * Wfc[t];
    __syncthreads();
    for (int d = 64; d > 0; d >>= 1) {
        if (t < d) s[t] += s[t + d];
        __syncthreads();
    }
    if (t == 0) out[0] = s[0] + bfc[0];
}

// ---------------- launch ----------------

extern "C" void kernel_launch(void* const* d_in, const int* in_sizes, int n_in,
                              void* d_out, int out_size, void* d_ws, size_t ws_size,
                              hipStream_t stream) {
    const float* x   = (const float*)d_in[0];
    const int*   ei  = (const int*)d_in[1];
    const float* W1  = (const float*)d_in[2];
    const float* b1  = (const float*)d_in[3];
    const float* W2  = (const float*)d_in[4];
    const float* b2  = (const float*)d_in[5];
    const float* Wfc = (const float*)d_in[6];
    const float* bfc = (const float*)d_in[7];
    float* out = (float*)d_out;

    int N = in_sizes[0] / FEAT;     // 50000
    int E = in_sizes[1] / 2;        // 800000
    const int* src = ei;
    const int* dst = ei + E;

    int NW = (E + TILE - 1) / TILE;
    int B  = (N + 1023) >> 10;

    char* p = (char*)d_ws;
    auto alloc = [&](size_t bytes) {
        char* r = p;
        p += (bytes + 255) & ~(size_t)255;
        return r;
    };
    int* cnt             = (int*)alloc((size_t)B * NW * 4);
    unsigned int* ebuf   = (unsigned int*)alloc((size_t)E * 4);
    unsigned short* csr  = (unsigned short*)alloc((size_t)E * 2);
    int* degi            = (int*)alloc((size_t)N * 4);
    float* isd           = (float*)alloc((size_t)N * 4);
    int* off             = (int*)alloc((size_t)(N + 1) * 4);
    int* bsum            = (int*)alloc(64 * 4);
    unsigned int* xq     = (unsigned int*)alloc((size_t)N * 32 * 4);   // fp8 x, scaled
    uint4* agg1b         = (uint4*)alloc((size_t)N * 16 * 16);         // bf16 agg1 rows
    unsigned char* t2q   = (unsigned char*)alloc((size_t)N * 128);     // fp8 t2, scaled
    unsigned short* w1z  = (unsigned short*)alloc(128 * 256 * 2);
    unsigned short* w2z  = (unsigned short*)alloc(256 * 128 * 2);
    float* pooled        = (float*)alloc(128 * 16 * 4);                // spread x16

    // --- CSR build ---
    k_p1<<<NW, 1024, 0, stream>>>(dst, cnt, E, B, NW);
    k_bscan<<<1, 1024, 0, stream>>>(cnt, B * NW);
    k_p3<<<NW, 1024, 0, stream>>>(src, dst, cnt, ebuf, E, B, NW);
    k_p4a<<<B, 1024, 0, stream>>>(ebuf, cnt, degi, isd, E, B, NW, N);
    int nb = (N + 1023) / 1024;
    k_scan1<<<nb, 1024, 0, stream>>>(degi, off, bsum, N);
    k_scan2<<<1, 64, 0, stream>>>(bsum, nb);
    k_scan3<<<(N + 1 + 255) / 256, 256, 0, stream>>>(off, bsum, N, E);
    k_p4b<<<B, 1024, 0, stream>>>(ebuf, cnt, off, csr, E, B, NW, N);

    // --- casts / weights ---
    int total4 = N * FEAT / 4;
    k_scalecast<<<(total4 + 255) / 256, 256, 0, stream>>>(x, isd, xq, pooled, total4);
    k_wswz<<<32, 256, 0, stream>>>(W1, w1z, W2, w2z);

    int gblk = (N + 63) / 64;

    // layer 1: aggregate(xq) -> fused GEMM(128->256->128), t2q fp8 pre-scaled
    k_agg8<0><<<(N + 3) / 4, 256, 0, stream>>>((const uint4*)xq, off, csr, isd, nullptr,
                                               agg1b, nullptr, N);
    k_gemm12<<<gblk, 256, 0, stream>>>((const unsigned short*)agg1b, w1z, b1, w2z, isd, t2q, N);

    // layer 2: aggregate(t2q) fused with +b2, relu, pool
    k_agg8<1><<<(N + 3) / 4, 256, 0, stream>>>((const uint4*)t2q, off, csr, isd, b2,
                                               nullptr, pooled, N);

    k_final<<<1, 128, 0, stream>>>(pooled, Wfc, bfc, out, 1.0f / (float)N);
}

// Round 6
// 264.864 us; speedup vs baseline: 1.9212x; 1.9212x over previous
//
#include <hip/hip_runtime.h>

// GCN: 2x GCNConv(sym-norm, self-loops) + mean-pool + linear head.
// Round 6: revert gather to whole-wave-per-node bf16 (round-4 structure,
// wave-uniform row index), unroll 8 for MLP. Keep fused GEMM1+GEMM2,
// bucketed CSR; fold deg/isd/off-scan into the bucket kernel (k_p4a).

#define FEAT 128
#define TILE 16384   // edges per bucketing workgroup

typedef __attribute__((ext_vector_type(8))) short short8;    // 8 bf16
typedef __attribute__((ext_vector_type(4))) float float4v;   // 4 fp32 acc

__device__ __forceinline__ unsigned int f2b(float f) {       // rne bf16 (as uint)
    unsigned int u = __float_as_uint(f);
    return (u + 0x7fffu + ((u >> 16) & 1u)) >> 16;
}
__device__ __forceinline__ float b_lo(unsigned int u) { return __uint_as_float(u << 16); }
__device__ __forceinline__ float b_hi(unsigned int u) { return __uint_as_float(u & 0xffff0000u); }

// ---------------- bucketed CSR build (bucket = dst>>10) ----------------

__global__ __launch_bounds__(1024) void k_p1(const int* __restrict__ dst,
                                             int* __restrict__ cnt, int E, int B, int NW) {
    __shared__ int h[64];
    int t = threadIdx.x, w = blockIdx.x;
    if (t < B) h[t] = 0;
    __syncthreads();
    int e0 = w * TILE, e1 = min(e0 + TILE, E);
    for (int e = e0 + t; e < e1; e += 1024) atomicAdd(&h[dst[e] >> 10], 1);
    __syncthreads();
    if (t < B) cnt[t * NW + w] = h[t];      // bucket-major
}

__global__ __launch_bounds__(1024) void k_bscan(int* __restrict__ cnt, int L) {
    __shared__ int s[1024];
    int t = threadIdx.x;
    int v[3]; int sum = 0;
#pragma unroll
    for (int j = 0; j < 3; ++j) {
        int idx = t * 3 + j;
        int x = (idx < L) ? cnt[idx] : 0;
        v[j] = sum; sum += x;
    }
    s[t] = sum;
    __syncthreads();
    for (int d = 1; d < 1024; d <<= 1) {
        int x = (t >= d) ? s[t - d] : 0;
        __syncthreads();
        s[t] += x;
        __syncthreads();
    }
    int pre = (t > 0) ? s[t - 1] : 0;
#pragma unroll
    for (int j = 0; j < 3; ++j) {
        int idx = t * 3 + j;
        if (idx < L) cnt[idx] = pre + v[j];
    }
}

__global__ __launch_bounds__(1024) void k_p3(const int* __restrict__ src,
                                             const int* __restrict__ dst,
                                             const int* __restrict__ cnt,
                                             unsigned int* __restrict__ ebuf,
                                             int E, int B, int NW) {
    __shared__ int cur[64];
    int t = threadIdx.x, w = blockIdx.x;
    if (t < B) cur[t] = cnt[t * NW + w];
    __syncthreads();
    int e0 = w * TILE, e1 = min(e0 + TILE, E);
    for (int e = e0 + t; e < e1; e += 1024) {
        int d = dst[e], s = src[e];
        int p = atomicAdd(&cur[d >> 10], 1);
        ebuf[p] = ((unsigned int)d << 16) | (unsigned int)s;
    }
}

// per bucket: node degree histogram -> isd, intra-bucket exclusive scan -> off
__global__ __launch_bounds__(1024) void k_p4a(const unsigned int* __restrict__ ebuf,
                                              const int* __restrict__ cnt,
                                              float* __restrict__ isd,
                                              int* __restrict__ off,
                                              int E, int B, int NW, int N) {
    __shared__ int h[1024];
    __shared__ int s[1024];
    int t = threadIdx.x, b = blockIdx.x;
    h[t] = 0;
    __syncthreads();
    int s0 = cnt[b * NW];
    int s1 = (b + 1 < B) ? cnt[(b + 1) * NW] : E;
    for (int e = s0 + t; e < s1; e += 1024)
        atomicAdd(&h[(ebuf[e] >> 16) & 1023], 1);
    __syncthreads();
    int own = h[t];
    s[t] = own;
    __syncthreads();
    for (int d = 1; d < 1024; d <<= 1) {
        int x = (t >= d) ? s[t - d] : 0;
        __syncthreads();
        s[t] += x;
        __syncthreads();
    }
    int node = (b << 10) + t;
    if (node < N) {
        isd[node] = rsqrtf((float)(own + 1));        // +1 self-loop
        off[node] = s0 + s[t] - own;                 // exclusive
        if (node == N - 1) off[N] = s0 + s[t];       // == E
    }
}

__global__ __launch_bounds__(1024) void k_p4b(const unsigned int* __restrict__ ebuf,
                                              const int* __restrict__ cnt,
                                              const int* __restrict__ off,
                                              unsigned short* __restrict__ csr,
                                              int E, int B, int NW, int N) {
    __shared__ int cur[1024];
    int t = threadIdx.x, b = blockIdx.x;
    int node = (b << 10) + t;
    cur[t] = (node < N) ? off[node] : 0;
    __syncthreads();
    int s0 = cnt[b * NW];
    int s1 = (b + 1 < B) ? cnt[(b + 1) * NW] : E;
    for (int e = s0 + t; e < s1; e += 1024) {
        unsigned int v = ebuf[e];
        int p = atomicAdd(&cur[(v >> 16) & 1023], 1);
        csr[p] = (unsigned short)(v & 0xffffu);
    }
}

// ---------------- casts ----------------

// xb[n] = bf16(isd[row] * x[n]); also zero pooled
__global__ void k_scalecast(const float* __restrict__ x, const float* __restrict__ isd,
                            uint2* __restrict__ xb, float* __restrict__ pooled,
                            int total4) {
    int i = blockIdx.x * blockDim.x + threadIdx.x;
    if (i < 128) pooled[i] = 0.f;
    if (i >= total4) return;
    float w = isd[i >> 5];
    float4 v = ((const float4*)x)[i];
    unsigned int lo = f2b(v.x * w) | (f2b(v.y * w) << 16);
    unsigned int hi = f2b(v.z * w) | (f2b(v.w * w) << 16);
    xb[i] = make_uint2(lo, hi);
}

// both weights -> bf16 MFMA B-fragment order, one launch
__device__ __forceinline__ void wswz_one(const float* W, unsigned short* out,
                                         int N, int tid) {
    int lane = tid & 63, f = tid >> 6;
    int NT = N >> 4;
    int nt = f % NT, kt = f / NT;
    int m = lane & 15, quad = lane >> 4;
    short8 pk;
#pragma unroll
    for (int j = 0; j < 8; ++j)
        pk[j] = (short)f2b(W[(size_t)(kt * 32 + quad * 8 + j) * N + nt * 16 + m]);
    *(short8*)(out + (size_t)tid * 8) = pk;
}

__global__ void k_wswz(const float* __restrict__ W1, unsigned short* __restrict__ w1z,
                       const float* __restrict__ W2, unsigned short* __restrict__ w2z) {
    int tid = blockIdx.x * blockDim.x + threadIdx.x;
    if (tid < 4096) wswz_one(W1, w1z, 256, tid);             // 128x256
    else if (tid < 8192) wswz_one(W2, w2z, 128, tid - 4096); // 256x128
}

// ---------------- aggregation (whole wave per node, wave-uniform row) --------
// out[n] = bf16( isd[n] * (sum_{s in N(n)} Xs[s] + Xs[n]) ), Xs pre-scaled.

__global__ __launch_bounds__(256) void k_agg(const unsigned int* __restrict__ Xb,
                                             const int* __restrict__ off,
                                             const unsigned short* __restrict__ csr,
                                             const float* __restrict__ isd,
                                             unsigned int* __restrict__ out, int n) {
    int wid  = (blockIdx.x * 256 + threadIdx.x) >> 6;
    int lane = threadIdx.x & 63;
    if (wid >= n) return;
    int beg = off[wid], end = off[wid + 1];
    float a0, a1;
    {
        unsigned int ux = Xb[(size_t)wid * 64 + lane];   // self term
        a0 = b_lo(ux); a1 = b_hi(ux);
    }
    int e = beg;
    for (; e + 8 <= end; e += 8) {                       // 8 gathers in flight
        int s0 = csr[e],     s1 = csr[e + 1], s2 = csr[e + 2], s3 = csr[e + 3];
        int s4 = csr[e + 4], s5 = csr[e + 5], s6 = csr[e + 6], s7 = csr[e + 7];
        unsigned int u0 = Xb[(size_t)s0 * 64 + lane];
        unsigned int u1 = Xb[(size_t)s1 * 64 + lane];
        unsigned int u2 = Xb[(size_t)s2 * 64 + lane];
        unsigned int u3 = Xb[(size_t)s3 * 64 + lane];
        unsigned int u4 = Xb[(size_t)s4 * 64 + lane];
        unsigned int u5 = Xb[(size_t)s5 * 64 + lane];
        unsigned int u6 = Xb[(size_t)s6 * 64 + lane];
        unsigned int u7 = Xb[(size_t)s7 * 64 + lane];
        a0 += b_lo(u0) + b_lo(u1) + b_lo(u2) + b_lo(u3)
            + b_lo(u4) + b_lo(u5) + b_lo(u6) + b_lo(u7);
        a1 += b_hi(u0) + b_hi(u1) + b_hi(u2) + b_hi(u3)
            + b_hi(u4) + b_hi(u5) + b_hi(u6) + b_hi(u7);
    }
    for (; e + 2 <= end; e += 2) {
        int s0 = csr[e], s1 = csr[e + 1];
        unsigned int u0 = Xb[(size_t)s0 * 64 + lane];
        unsigned int u1 = Xb[(size_t)s1 * 64 + lane];
        a0 += b_lo(u0) + b_lo(u1);
        a1 += b_hi(u0) + b_hi(u1);
    }
    if (e < end) {
        unsigned int u0 = Xb[(size_t)csr[e] * 64 + lane];
        a0 += b_lo(u0);
        a1 += b_hi(u0);
    }
    float wn = isd[wid];
    out[(size_t)wid * 64 + lane] = f2b(wn * a0) | (f2b(wn * a1) << 16);
}

// ---------------- fused GEMM1+GEMM2 ----------------
// stage1: h1 = relu(A@W1 + b1)   (A bf16 [M,128], W1 128x256) -> LDS tile
// stage2: t2 = bf16(isd[row] * (h1@W2))   (W2 256x128) -> global

__global__ __launch_bounds__(256) void k_gemm12(const unsigned short* __restrict__ A,
                                                const unsigned short* __restrict__ W1z,
                                                const float* __restrict__ b1,
                                                const unsigned short* __restrict__ W2z,
                                                const float* __restrict__ isd,
                                                unsigned short* __restrict__ t2, int M) {
    __shared__ unsigned short h1s[64 * 272];     // 64 rows x 256 cols, stride 272
    int tid = threadIdx.x;
    int lane = tid & 63, wm = tid >> 6;
    int m = lane & 15, quad = lane >> 4;

    long arow = (long)blockIdx.x * 64 + wm * 16 + m;
    if (arow >= M) arow = M - 1;
    const short8* Ap  = (const short8*)(A + (size_t)arow * 128);
    const short8* W1p = (const short8*)W1z + lane;

    float4v acc1[16];
    float4v zero = {0.f, 0.f, 0.f, 0.f};
#pragma unroll
    for (int nt = 0; nt < 16; ++nt) acc1[nt] = zero;
#pragma unroll
    for (int kt = 0; kt < 4; ++kt) {
        short8 a = Ap[kt * 4 + quad];
#pragma unroll
        for (int nt = 0; nt < 16; ++nt)
            acc1[nt] = __builtin_amdgcn_mfma_f32_16x16x32_bf16(a, W1p[(kt * 16 + nt) * 64],
                                                               acc1[nt], 0, 0, 0);
    }
    int r0 = wm * 16 + quad * 4;                 // block-local rows
#pragma unroll
    for (int nt = 0; nt < 16; ++nt) {
        int col = nt * 16 + m;
        float bz = b1[col];
#pragma unroll
        for (int reg = 0; reg < 4; ++reg) {
            float v = fmaxf(acc1[nt][reg] + bz, 0.f);
            h1s[(r0 + reg) * 272 + col] = (unsigned short)f2b(v);
        }
    }
    __syncthreads();

    float4v acc2[8];
#pragma unroll
    for (int nt = 0; nt < 8; ++nt) acc2[nt] = zero;
    const short8* W2p = (const short8*)W2z + lane;
    int rloc = wm * 16 + m;
#pragma unroll
    for (int kt = 0; kt < 8; ++kt) {
        short8 a2 = *(const short8*)(h1s + rloc * 272 + kt * 32 + quad * 8);
#pragma unroll
        for (int nt = 0; nt < 8; ++nt)
            acc2[nt] = __builtin_amdgcn_mfma_f32_16x16x32_bf16(a2, W2p[(kt * 8 + nt) * 64],
                                                               acc2[nt], 0, 0, 0);
    }
    int gr0 = blockIdx.x * 64 + wm * 16 + quad * 4;
    float sc[4];
#pragma unroll
    for (int reg = 0; reg < 4; ++reg) {
        int r = gr0 + reg;
        sc[reg] = (r < M) ? isd[r] : 0.f;
    }
#pragma unroll
    for (int nt = 0; nt < 8; ++nt) {
        int col = nt * 16 + m;
#pragma unroll
        for (int reg = 0; reg < 4; ++reg) {
            int gr = gr0 + reg;
            if (gr < M)
                t2[(size_t)gr * 128 + col] = (unsigned short)f2b(acc2[nt][reg] * sc[reg]);
        }
    }
}

// ---------------- pool: pooled[f] += sum_n relu(agg2[n][f] + b2[f])

__global__ __launch_bounds__(256) void k_post(const unsigned int* __restrict__ agg2,
                                              const float* __restrict__ b2,
                                              float* __restrict__ pooled, int n) {
    __shared__ float s0[256], s1[256];
    int f2 = threadIdx.x & 63;       // feature pair
    int rg = threadIdx.x >> 6;       // 0..3 rows in flight
    float bz0 = b2[2 * f2], bz1 = b2[2 * f2 + 1];
    float a0 = 0.f, a1 = 0.f;
    for (int r = blockIdx.x * 4 + rg; r < n; r += gridDim.x * 4) {
        unsigned int u = agg2[(size_t)r * 64 + f2];
        a0 += fmaxf(b_lo(u) + bz0, 0.f);
        a1 += fmaxf(b_hi(u) + bz1, 0.f);
    }
    s0[threadIdx.x] = a0;
    s1[threadIdx.x] = a1;
    __syncthreads();
    if (rg == 0) {
        float t0 = s0[f2] + s0[64 + f2] + s0[128 + f2] + s0[192 + f2];
        float t1 = s1[f2] + s1[64 + f2] + s1[128 + f2] + s1[192 + f2];
        atomicAdd(&pooled[2 * f2], t0);
        atomicAdd(&pooled[2 * f2 + 1], t1);
    }
}

__global__ void k_final(const float* __restrict__ pooled,
                        const float* __restrict__ Wfc,
                        const float* __restrict__ bfc,
                        float* __restrict__ out, float invN) {
    __shared__ float s[128];
    int t = threadIdx.x;
    s[t] = pooled[t] * invN * Wfc[t];
    __syncthreads();
    for (int d = 64; d > 0; d >>= 1) {
        if (t < d) s[t] += s[t + d];
        __syncthreads();
    }
    if (t == 0) out[0] = s[0] + bfc[0];
}

// ---------------- launch ----------------

extern "C" void kernel_launch(void* const* d_in, const int* in_sizes, int n_in,
                              void* d_out, int out_size, void* d_ws, size_t ws_size,
                              hipStream_t stream) {
    const float* x   = (const float*)d_in[0];
    const int*   ei  = (const int*)d_in[1];
    const float* W1  = (const float*)d_in[2];
    const float* b1  = (const float*)d_in[3];
    const float* W2  = (const float*)d_in[4];
    const float* b2  = (const float*)d_in[5];
    const float* Wfc = (const float*)d_in[6];
    const float* bfc = (const float*)d_in[7];
    float* out = (float*)d_out;

    int N = in_sizes[0] / FEAT;     // 50000
    int E = in_sizes[1] / 2;        // 800000
    const int* src = ei;
    const int* dst = ei + E;

    int NW = (E + TILE - 1) / TILE;
    int B  = (N + 1023) >> 10;

    char* p = (char*)d_ws;
    auto alloc = [&](size_t bytes) {
        char* r = p;
        p += (bytes + 255) & ~(size_t)255;
        return r;
    };
    int* cnt             = (int*)alloc((size_t)B * NW * 4);
    unsigned int* ebuf   = (unsigned int*)alloc((size_t)E * 4);
    unsigned short* csr  = (unsigned short*)alloc((size_t)E * 2);
    float* isd           = (float*)alloc((size_t)N * 4);
    int* off             = (int*)alloc((size_t)(N + 1) * 4);
    uint2* xb            = (uint2*)alloc((size_t)N * 32 * 8);          // bf16 x pre-scaled
    unsigned int* agg1b  = (unsigned int*)alloc((size_t)N * 64 * 4);   // bf16 agg1
    unsigned short* t2b  = (unsigned short*)alloc((size_t)N * 128 * 2);// bf16 t2 pre-scaled
    unsigned int* ag2b   = (unsigned int*)alloc((size_t)N * 64 * 4);   // bf16 agg2
    unsigned short* w1z  = (unsigned short*)alloc(128 * 256 * 2);
    unsigned short* w2z  = (unsigned short*)alloc(256 * 128 * 2);
    float* pooled        = (float*)alloc(128 * 4);

    // --- CSR build ---
    k_p1<<<NW, 1024, 0, stream>>>(dst, cnt, E, B, NW);
    k_bscan<<<1, 1024, 0, stream>>>(cnt, B * NW);
    k_p3<<<NW, 1024, 0, stream>>>(src, dst, cnt, ebuf, E, B, NW);
    k_p4a<<<B, 1024, 0, stream>>>(ebuf, cnt, isd, off, E, B, NW, N);
    k_p4b<<<B, 1024, 0, stream>>>(ebuf, cnt, off, csr, E, B, NW, N);

    // --- casts / weights ---
    int total4 = N * FEAT / 4;
    k_scalecast<<<(total4 + 255) / 256, 256, 0, stream>>>(x, isd, xb, pooled, total4);
    k_wswz<<<32, 256, 0, stream>>>(W1, w1z, W2, w2z);

    int gblk = (N + 63) / 64;

    // layer 1: aggregate -> fused GEMM(128->256->128) with isd pre-scale
    k_agg<<<(N + 3) / 4, 256, 0, stream>>>((const unsigned int*)xb, off, csr, isd, agg1b, N);
    k_gemm12<<<gblk, 256, 0, stream>>>((const unsigned short*)agg1b, w1z, b1, w2z, isd, t2b, N);

    // layer 2: aggregate -> (+b2, relu, pool)
    k_agg<<<(N + 3) / 4, 256, 0, stream>>>((const unsigned int*)t2b, off, csr, isd, ag2b, N);
    k_post<<<512, 256, 0, stream>>>(ag2b, b2, pooled, N);
    k_final<<<1, 128, 0, stream>>>(pooled, Wfc, bfc, out, 1.0f / (float)N);
}

// Round 7
// 245.682 us; speedup vs baseline: 2.0712x; 1.0781x over previous
//
#include <hip/hip_runtime.h>

// GCN: 2x GCNConv(sym-norm, self-loops) + mean-pool + linear head.
// Round 7: fp8(e4m3, x16*isd-scaled) gather arrays in round-6's wave-uniform
// gather structure (lane = ushort = 2 fp8 feats); merged p4a+p4b; bf16 MFMA
// fused GEMM1+GEMM2 unchanged. fp32 accumulation everywhere.

#define FEAT 128
#define TILE 16384   // edges per bucketing workgroup

typedef __attribute__((ext_vector_type(8))) short short8;    // 8 bf16
typedef __attribute__((ext_vector_type(4))) float float4v;   // 4 fp32 acc
typedef __attribute__((ext_vector_type(2))) float floatx2;

__device__ __forceinline__ unsigned int f2b(float f) {       // rne bf16 (as uint)
    unsigned int u = __float_as_uint(f);
    return (u + 0x7fffu + ((u >> 16) & 1u)) >> 16;
}
__device__ __forceinline__ float b_lo(unsigned int u) { return __uint_as_float(u << 16); }
__device__ __forceinline__ float b_hi(unsigned int u) { return __uint_as_float(u & 0xffff0000u); }

// ---------------- bucketed CSR build (bucket = dst>>10) ----------------

__global__ __launch_bounds__(1024) void k_p1(const int* __restrict__ dst,
                                             int* __restrict__ cnt, int E, int B, int NW) {
    __shared__ int h[64];
    int t = threadIdx.x, w = blockIdx.x;
    if (t < B) h[t] = 0;
    __syncthreads();
    int e0 = w * TILE, e1 = min(e0 + TILE, E);
    for (int e = e0 + t; e < e1; e += 1024) atomicAdd(&h[dst[e] >> 10], 1);
    __syncthreads();
    if (t < B) cnt[t * NW + w] = h[t];      // bucket-major
}

__global__ __launch_bounds__(1024) void k_bscan(int* __restrict__ cnt, int L) {
    __shared__ int s[1024];
    int t = threadIdx.x;
    int v[3]; int sum = 0;
#pragma unroll
    for (int j = 0; j < 3; ++j) {
        int idx = t * 3 + j;
        int x = (idx < L) ? cnt[idx] : 0;
        v[j] = sum; sum += x;
    }
    s[t] = sum;
    __syncthreads();
    for (int d = 1; d < 1024; d <<= 1) {
        int x = (t >= d) ? s[t - d] : 0;
        __syncthreads();
        s[t] += x;
        __syncthreads();
    }
    int pre = (t > 0) ? s[t - 1] : 0;
#pragma unroll
    for (int j = 0; j < 3; ++j) {
        int idx = t * 3 + j;
        if (idx < L) cnt[idx] = pre + v[j];
    }
}

__global__ __launch_bounds__(1024) void k_p3(const int* __restrict__ src,
                                             const int* __restrict__ dst,
                                             const int* __restrict__ cnt,
                                             unsigned int* __restrict__ ebuf,
                                             int E, int B, int NW) {
    __shared__ int cur[64];
    int t = threadIdx.x, w = blockIdx.x;
    if (t < B) cur[t] = cnt[t * NW + w];
    __syncthreads();
    int e0 = w * TILE, e1 = min(e0 + TILE, E);
    for (int e = e0 + t; e < e1; e += 1024) {
        int d = dst[e], s = src[e];
        int p = atomicAdd(&cur[d >> 10], 1);
        ebuf[p] = ((unsigned int)d << 16) | (unsigned int)s;
    }
}

// merged: per bucket histogram -> isd, intra-bucket scan -> off, scatter -> csr
__global__ __launch_bounds__(1024) void k_p4(const unsigned int* __restrict__ ebuf,
                                             const int* __restrict__ cnt,
                                             float* __restrict__ isd,
                                             int* __restrict__ off,
                                             unsigned short* __restrict__ csr,
                                             int E, int B, int NW, int N) {
    __shared__ int h[1024];
    __shared__ int s[1024];
    __shared__ int cur[1024];
    int t = threadIdx.x, b = blockIdx.x;
    h[t] = 0;
    __syncthreads();
    int s0 = cnt[b * NW];
    int s1 = (b + 1 < B) ? cnt[(b + 1) * NW] : E;
    for (int e = s0 + t; e < s1; e += 1024)
        atomicAdd(&h[(ebuf[e] >> 16) & 1023], 1);
    __syncthreads();
    int own = h[t];
    s[t] = own;
    __syncthreads();
    for (int d = 1; d < 1024; d <<= 1) {
        int x = (t >= d) ? s[t - d] : 0;
        __syncthreads();
        s[t] += x;
        __syncthreads();
    }
    int node = (b << 10) + t;
    int myoff = s0 + s[t] - own;
    cur[t] = myoff;
    if (node < N) {
        isd[node] = rsqrtf((float)(own + 1));        // +1 self-loop
        off[node] = myoff;
        if (node == N - 1) off[N] = s0 + s[t];       // == E
    }
    __syncthreads();
    for (int e = s0 + t; e < s1; e += 1024) {
        unsigned int v = ebuf[e];
        int p = atomicAdd(&cur[(v >> 16) & 1023], 1);
        csr[p] = (unsigned short)(v & 0xffffu);
    }
}

// ---------------- casts ----------------

// xq[4i..4i+3] = fp8(16*isd[row] * x[..]); one uint (4 fp8) per thread
__global__ void k_scalecast(const float* __restrict__ x, const float* __restrict__ isd,
                            unsigned int* __restrict__ xq, float* __restrict__ pooled,
                            int total4) {
    int i = blockIdx.x * blockDim.x + threadIdx.x;
    if (i < 128) pooled[i] = 0.f;
    if (i >= total4) return;
    float w = isd[i >> 5] * 16.f;
    float4 v = ((const float4*)x)[i];
    unsigned int u = __builtin_amdgcn_cvt_pk_fp8_f32(v.x * w, v.y * w, 0u, false);
    u = __builtin_amdgcn_cvt_pk_fp8_f32(v.z * w, v.w * w, u, true);
    xq[i] = u;
}

// both weights -> bf16 MFMA B-fragment order, one launch
__device__ __forceinline__ void wswz_one(const float* W, unsigned short* out,
                                         int N, int tid) {
    int lane = tid & 63, f = tid >> 6;
    int NT = N >> 4;
    int nt = f % NT, kt = f / NT;
    int m = lane & 15, quad = lane >> 4;
    short8 pk;
#pragma unroll
    for (int j = 0; j < 8; ++j)
        pk[j] = (short)f2b(W[(size_t)(kt * 32 + quad * 8 + j) * N + nt * 16 + m]);
    *(short8*)(out + (size_t)tid * 8) = pk;
}

__global__ void k_wswz(const float* __restrict__ W1, unsigned short* __restrict__ w1z,
                       const float* __restrict__ W2, unsigned short* __restrict__ w2z) {
    int tid = blockIdx.x * blockDim.x + threadIdx.x;
    if (tid < 4096) wswz_one(W1, w1z, 256, tid);             // 128x256
    else if (tid < 8192) wswz_one(W2, w2z, 128, tid - 4096); // 256x128
}

// ---------------- aggregation (whole wave per node, fp8 rows) ---------------
// out[n] = bf16( isd[n] * (sum_{s in N(n)} Xs[s] + Xs[n]) ), Xs = fp8(16*isd*X)
// lane owns feats {2*lane, 2*lane+1}: one ushort (2 fp8) per row.

__global__ __launch_bounds__(256) void k_agg(const unsigned short* __restrict__ Xq,
                                             const int* __restrict__ off,
                                             const unsigned short* __restrict__ csr,
                                             const float* __restrict__ isd,
                                             unsigned int* __restrict__ out, int n) {
    int wid  = (blockIdx.x * 256 + threadIdx.x) >> 6;
    int lane = threadIdx.x & 63;
    if (wid >= n) return;
    wid = __builtin_amdgcn_readfirstlane(wid);           // provably wave-uniform
    int beg = off[wid], end = off[wid + 1];
    float a0, a1;
    {
        unsigned int q = Xq[(size_t)wid * 64 + lane];    // self term
        floatx2 f = __builtin_amdgcn_cvt_pk_f32_fp8(q, false);
        a0 = f[0]; a1 = f[1];
    }
    int e = beg;
    for (; e + 8 <= end; e += 8) {                       // 8 gathers in flight
        int s0 = csr[e],     s1 = csr[e + 1], s2 = csr[e + 2], s3 = csr[e + 3];
        int s4 = csr[e + 4], s5 = csr[e + 5], s6 = csr[e + 6], s7 = csr[e + 7];
        unsigned int q0 = Xq[(size_t)s0 * 64 + lane];
        unsigned int q1 = Xq[(size_t)s1 * 64 + lane];
        unsigned int q2 = Xq[(size_t)s2 * 64 + lane];
        unsigned int q3 = Xq[(size_t)s3 * 64 + lane];
        unsigned int q4 = Xq[(size_t)s4 * 64 + lane];
        unsigned int q5 = Xq[(size_t)s5 * 64 + lane];
        unsigned int q6 = Xq[(size_t)s6 * 64 + lane];
        unsigned int q7 = Xq[(size_t)s7 * 64 + lane];
        floatx2 f0 = __builtin_amdgcn_cvt_pk_f32_fp8(q0, false);
        floatx2 f1 = __builtin_amdgcn_cvt_pk_f32_fp8(q1, false);
        floatx2 f2 = __builtin_amdgcn_cvt_pk_f32_fp8(q2, false);
        floatx2 f3 = __builtin_amdgcn_cvt_pk_f32_fp8(q3, false);
        floatx2 f4 = __builtin_amdgcn_cvt_pk_f32_fp8(q4, false);
        floatx2 f5 = __builtin_amdgcn_cvt_pk_f32_fp8(q5, false);
        floatx2 f6 = __builtin_amdgcn_cvt_pk_f32_fp8(q6, false);
        floatx2 f7 = __builtin_amdgcn_cvt_pk_f32_fp8(q7, false);
        a0 += f0[0] + f1[0] + f2[0] + f3[0] + f4[0] + f5[0] + f6[0] + f7[0];
        a1 += f0[1] + f1[1] + f2[1] + f3[1] + f4[1] + f5[1] + f6[1] + f7[1];
    }
    for (; e + 2 <= end; e += 2) {
        int s0 = csr[e], s1 = csr[e + 1];
        unsigned int q0 = Xq[(size_t)s0 * 64 + lane];
        unsigned int q1 = Xq[(size_t)s1 * 64 + lane];
        floatx2 f0 = __builtin_amdgcn_cvt_pk_f32_fp8(q0, false);
        floatx2 f1 = __builtin_amdgcn_cvt_pk_f32_fp8(q1, false);
        a0 += f0[0] + f1[0];
        a1 += f0[1] + f1[1];
    }
    if (e < end) {
        unsigned int q0 = Xq[(size_t)csr[e] * 64 + lane];
        floatx2 f0 = __builtin_amdgcn_cvt_pk_f32_fp8(q0, false);
        a0 += f0[0];
        a1 += f0[1];
    }
    float wn = isd[wid] * 0.0625f;                       // undo the x16 fp8 scale
    out[(size_t)wid * 64 + lane] = f2b(wn * a0) | (f2b(wn * a1) << 16);
}

// ---------------- fused GEMM1+GEMM2 ----------------
// stage1: h1 = relu(A@W1 + b1)   (A bf16 [M,128], W1 128x256) -> LDS tile
// stage2: t2q = fp8(16*isd[row] * (h1@W2))   (W2 256x128) -> global

__global__ __launch_bounds__(256) void k_gemm12(const unsigned short* __restrict__ A,
                                                const unsigned short* __restrict__ W1z,
                                                const float* __restrict__ b1,
                                                const unsigned short* __restrict__ W2z,
                                                const float* __restrict__ isd,
                                                unsigned char* __restrict__ t2q, int M) {
    __shared__ unsigned short h1s[64 * 272];     // 64 rows x 256 cols, stride 272
    int tid = threadIdx.x;
    int lane = tid & 63, wm = tid >> 6;
    int m = lane & 15, quad = lane >> 4;

    long arow = (long)blockIdx.x * 64 + wm * 16 + m;
    if (arow >= M) arow = M - 1;
    const short8* Ap  = (const short8*)(A + (size_t)arow * 128);
    const short8* W1p = (const short8*)W1z + lane;

    float4v acc1[16];
    float4v zero = {0.f, 0.f, 0.f, 0.f};
#pragma unroll
    for (int nt = 0; nt < 16; ++nt) acc1[nt] = zero;
#pragma unroll
    for (int kt = 0; kt < 4; ++kt) {
        short8 a = Ap[kt * 4 + quad];
#pragma unroll
        for (int nt = 0; nt < 16; ++nt)
            acc1[nt] = __builtin_amdgcn_mfma_f32_16x16x32_bf16(a, W1p[(kt * 16 + nt) * 64],
                                                               acc1[nt], 0, 0, 0);
    }
    int r0 = wm * 16 + quad * 4;                 // block-local rows
#pragma unroll
    for (int nt = 0; nt < 16; ++nt) {
        int col = nt * 16 + m;
        float bz = b1[col];
#pragma unroll
        for (int reg = 0; reg < 4; ++reg) {
            float v = fmaxf(acc1[nt][reg] + bz, 0.f);
            h1s[(r0 + reg) * 272 + col] = (unsigned short)f2b(v);
        }
    }
    __syncthreads();

    float4v acc2[8];
#pragma unroll
    for (int nt = 0; nt < 8; ++nt) acc2[nt] = zero;
    const short8* W2p = (const short8*)W2z + lane;
    int rloc = wm * 16 + m;
#pragma unroll
    for (int kt = 0; kt < 8; ++kt) {
        short8 a2 = *(const short8*)(h1s + rloc * 272 + kt * 32 + quad * 8);
#pragma unroll
        for (int nt = 0; nt < 8; ++nt)
            acc2[nt] = __builtin_amdgcn_mfma_f32_16x16x32_bf16(a2, W2p[(kt * 8 + nt) * 64],
                                                               acc2[nt], 0, 0, 0);
    }
    int gr0 = blockIdx.x * 64 + wm * 16 + quad * 4;
    float sc[4];
#pragma unroll
    for (int reg = 0; reg < 4; ++reg) {
        int r = gr0 + reg;
        sc[reg] = ((r < M) ? isd[r] : 0.f) * 16.f;
    }
#pragma unroll
    for (int nt = 0; nt < 8; ++nt) {
        int col = nt * 16 + m;
#pragma unroll
        for (int reg = 0; reg < 4; ++reg) {
            int gr = gr0 + reg;
            if (gr < M) {
                float v = acc2[nt][reg] * sc[reg];
                unsigned int b = __builtin_amdgcn_cvt_pk_fp8_f32(v, v, 0u, false);
                t2q[(size_t)gr * 128 + col] = (unsigned char)(b & 0xffu);
            }
        }
    }
}

// ---------------- pool: pooled[f] += sum_n relu(agg2[n][f] + b2[f])

__global__ __launch_bounds__(256) void k_post(const unsigned int* __restrict__ agg2,
                                              const float* __restrict__ b2,
                                              float* __restrict__ pooled, int n) {
    __shared__ float s0[256], s1[256];
    int f2 = threadIdx.x & 63;       // feature pair
    int rg = threadIdx.x >> 6;       // 0..3 rows in flight
    float bz0 = b2[2 * f2], bz1 = b2[2 * f2 + 1];
    float a0 = 0.f, a1 = 0.f;
    for (int r = blockIdx.x * 4 + rg; r < n; r += gridDim.x * 4) {
        unsigned int u = agg2[(size_t)r * 64 + f2];
        a0 += fmaxf(b_lo(u) + bz0, 0.f);
        a1 += fmaxf(b_hi(u) + bz1, 0.f);
    }
    s0[threadIdx.x] = a0;
    s1[threadIdx.x] = a1;
    __syncthreads();
    if (rg == 0) {
        float t0 = s0[f2] + s0[64 + f2] + s0[128 + f2] + s0[192 + f2];
        float t1 = s1[f2] + s1[64 + f2] + s1[128 + f2] + s1[192 + f2];
        atomicAdd(&pooled[2 * f2], t0);
        atomicAdd(&pooled[2 * f2 + 1], t1);
    }
}

__global__ void k_final(const float* __restrict__ pooled,
                        const float* __restrict__ Wfc,
                        const float* __restrict__ bfc,
                        float* __restrict__ out, float invN) {
    __shared__ float s[128];
    int t = threadIdx.x;
    s[t] = pooled[t] * invN * Wfc[t];
    __syncthreads();
    for (int d = 64; d > 0; d >>= 1) {
        if (t < d) s[t] += s[t + d];
        __syncthreads();
    }
    if (t == 0) out[0] = s[0] + bfc[0];
}

// ---------------- launch ----------------

extern "C" void kernel_launch(void* const* d_in, const int* in_sizes, int n_in,
                              void* d_out, int out_size, void* d_ws, size_t ws_size,
                              hipStream_t stream) {
    const float* x   = (const float*)d_in[0];
    const int*   ei  = (const int*)d_in[1];
    const float* W1  = (const float*)d_in[2];
    const float* b1  = (const float*)d_in[3];
    const float* W2  = (const float*)d_in[4];
    const float* b2  = (const float*)d_in[5];
    const float* Wfc = (const float*)d_in[6];
    const float* bfc = (const float*)d_in[7];
    float* out = (float*)d_out;

    int N = in_sizes[0] / FEAT;     // 50000
    int E = in_sizes[1] / 2;        // 800000
    const int* src = ei;
    const int* dst = ei + E;

    int NW = (E + TILE - 1) / TILE;
    int B  = (N + 1023) >> 10;

    char* p = (char*)d_ws;
    auto alloc = [&](size_t bytes) {
        char* r = p;
        p += (bytes + 255) & ~(size_t)255;
        return r;
    };
    int* cnt             = (int*)alloc((size_t)B * NW * 4);
    unsigned int* ebuf   = (unsigned int*)alloc((size_t)E * 4);
    unsigned short* csr  = (unsigned short*)alloc((size_t)E * 2);
    float* isd           = (float*)alloc((size_t)N * 4);
    int* off             = (int*)alloc((size_t)(N + 1) * 4);
    unsigned int* xq     = (unsigned int*)alloc((size_t)N * 32 * 4);   // fp8 x, x16*isd
    unsigned int* agg1b  = (unsigned int*)alloc((size_t)N * 64 * 4);   // bf16 agg1
    unsigned char* t2q   = (unsigned char*)alloc((size_t)N * 128);     // fp8 t2, x16*isd
    unsigned int* ag2b   = (unsigned int*)alloc((size_t)N * 64 * 4);   // bf16 agg2
    unsigned short* w1z  = (unsigned short*)alloc(128 * 256 * 2);
    unsigned short* w2z  = (unsigned short*)alloc(256 * 128 * 2);
    float* pooled        = (float*)alloc(128 * 4);

    // --- CSR build ---
    k_p1<<<NW, 1024, 0, stream>>>(dst, cnt, E, B, NW);
    k_bscan<<<1, 1024, 0, stream>>>(cnt, B * NW);
    k_p3<<<NW, 1024, 0, stream>>>(src, dst, cnt, ebuf, E, B, NW);
    k_p4<<<B, 1024, 0, stream>>>(ebuf, cnt, isd, off, csr, E, B, NW, N);

    // --- casts / weights ---
    int total4 = N * FEAT / 4;
    k_scalecast<<<(total4 + 255) / 256, 256, 0, stream>>>(x, isd, xq, pooled, total4);
    k_wswz<<<32, 256, 0, stream>>>(W1, w1z, W2, w2z);

    int gblk = (N + 63) / 64;

    // layer 1: aggregate(fp8) -> fused GEMM(128->256->128), t2q fp8 pre-scaled
    k_agg<<<(N + 3) / 4, 256, 0, stream>>>((const unsigned short*)xq, off, csr, isd, agg1b, N);
    k_gemm12<<<gblk, 256, 0, stream>>>((const unsigned short*)agg1b, w1z, b1, w2z, isd, t2q, N);

    // layer 2: aggregate(fp8) -> (+b2, relu, pool)
    k_agg<<<(N + 3) / 4, 256, 0, stream>>>((const unsigned short*)t2q, off, csr, isd, ag2b, N);
    k_post<<<512, 256, 0, stream>>>(ag2b, b2, pooled, N);
    k_final<<<1, 128, 0, stream>>>(pooled, Wfc, bfc, out, 1.0f / (float)N);
}